// Round 1
// 190.691 us; speedup vs baseline: 1.0209x; 1.0209x over previous
//
#include <hip/hip_runtime.h>

// DSQG attention, J=12 causal offsets, f32.
// One 16-lane group per position; lane holds 4 channels (float4).
// R3: latency-bound fix —
//   * __launch_bounds__(256,3): register budget matched to MEASURED occupancy
//     (~3 waves/SIMD); 56-VGPR build could not keep kr[12]+vr[12] in flight.
//   * all 25 global loads issued before any consumption (q, k*12, v*12, y/z).
//   * 16-lane allreduce via DPP (quad_perm xor1/xor2 + row_ror:4/:8) — pure
//     VALU, replaces 48 ds_bpermute + lgkm round-trips.
//   * SGPR-base + 32-bit byte-offset addressing; per-offset delta is the
//     literal d*256 (one v_add + v_cndmask per load).
//   * se folded into k before the dot: q.(k+se) = 4 add + 4 fma.
//   * raw v_rcp for the normalize (absmax tol 2^-7 >> 1 ulp).

namespace {

constexpr int J   = 12;
constexpr int B_  = 2;
constexpr int H_  = 16;
constexpr int N_  = 4096;
constexpr int HD_ = 64;
constexpr int OFFS[J] = {1, 2, 4, 8, 16, 64, 96, 192, 384, 512, 768, 1024};

// p += dpp_mov(p); CTRL must be an ICE, hence the template.
template <int CTRL>
__device__ __forceinline__ float dpp_add(float x) {
    int s = __builtin_amdgcn_update_dpp(0, __builtin_bit_cast(int, x),
                                        CTRL, 0xF, 0xF, false);
    return x + __builtin_bit_cast(float, s);
}

__global__ __launch_bounds__(256, 3) void dsqg_kernel(
    const float* __restrict__ q, const float* __restrict__ k,
    const float* __restrict__ v, const float* __restrict__ pb,
    const float* __restrict__ se, const float* __restrict__ phase_base,
    const float* __restrict__ phase_gain, const float* __restrict__ y_pre,
    const float* __restrict__ z_pre, float* __restrict__ out)
{
    // XCD-locality swizzle: contiguous work range per XCD so k/v row re-reads
    // (reuse window <= 1024 rows = 512 KB) stay in that XCD's 4 MB L2.
    const int raw = blockIdx.x;
    const int per = gridDim.x >> 3;
    const int wid = (raw & 7) * per + (raw >> 3);

    const int bh    = wid >> 8;       // 256 blocks (16 positions each) per (b,h)
    const int chunk = wid & 255;
    const int h     = bh & (H_ - 1);

    const int lane = threadIdx.x & 63;
    const int wave = threadIdx.x >> 6;
    const int grp  = lane & 15;                        // lane within position group
    const int n    = chunk * 16 + wave * 4 + (lane >> 4);

    // uniform (SGPR) per-(b,h) base pointers; per-lane 32-bit byte offsets
    const size_t bhbytes = (size_t)bh * (N_ * HD_ * 4);
    const char* qb = (const char*)q + bhbytes;
    const char* kb = (const char*)k + bhbytes;
    const char* vb = (const char*)v + bhbytes;
    char*       ob = (char*)out + bhbytes;

    const uint32_t gb   = (uint32_t)grp << 4;              // lane's float4 in a row
    const uint32_t rowb = ((uint32_t)n << 8) + gb;         // this position's slot

    const float4 qr = *(const float4*)(qb + rowb);

    bool ok[J];
    uint32_t offb[J];                 // byte offset of k/v row slot (clamped)
#pragma unroll
    for (int i = 0; i < J; ++i) {
        ok[i]   = (n >= OFFS[i]);
        offb[i] = ok[i] ? (rowb - ((uint32_t)OFFS[i] << 8)) : gb;
    }

    // ---- issue ALL global loads before any consumption ----------------------
    float4 kr[J];
#pragma unroll
    for (int i = 0; i < J; ++i) kr[i] = *(const float4*)(kb + offb[i]);

    float4 vr[J];
#pragma unroll
    for (int i = 0; i < J; ++i) vr[i] = *(const float4*)(vb + offb[i]);

    float2 zr[8];
    float2 yp = make_float2(0.f, 0.f);
    if (grp == 0) {                   // phase features only needed on ch0-3 lanes
        const char* yb = (const char*)y_pre + (size_t)bh * (N_ * 8);
        const char* zb = (const char*)z_pre + (size_t)bh * (N_ * 8);
        const uint32_t nb8 = (uint32_t)n << 3;
        yp = *(const float2*)(yb + nb8);
#pragma unroll
        for (int pi = 0; pi < 8; ++pi) {
            const uint32_t zo =
                ok[pi + 4] ? (nb8 - ((uint32_t)OFFS[pi + 4] << 3)) : 0u;
            zr[pi] = *(const float2*)(zb + zo);
        }
    }

    // ---- partial dots: p_i = q . (k_i + se_i) (per-lane 4-channel partial) --
    float p[J];
#pragma unroll
    for (int i = 0; i < J; ++i) {
        const float4 seg = ((const float4*)se)[i * 16 + grp];
        float t = qr.x * (kr[i].x + seg.x);
        t = fmaf(qr.y, kr[i].y + seg.y, t);
        t = fmaf(qr.z, kr[i].z + seg.z, t);
        p[i] = fmaf(qr.w, kr[i].w + seg.w, t);
    }

    // ---- 16-lane allreduce, pure VALU DPP (no LDS pipe) ---------------------
    // xor1, xor2 (quad_perm) reduce within quads; ror4+ror8 sum the 4
    // replicated quad-sums across the row -> every lane holds the full dot.
#pragma unroll
    for (int i = 0; i < J; ++i) {
        p[i] = dpp_add<0xB1>(p[i]);    // quad_perm [1,0,3,2]  : xor 1
        p[i] = dpp_add<0x4E>(p[i]);    // quad_perm [2,3,0,1]  : xor 2
        p[i] = dpp_add<0x124>(p[i]);   // row_ror:4
        p[i] = dpp_add<0x128>(p[i]);   // row_ror:8
    }

    const float sc = 0.125f;  // 1/sqrt(64)
    float e[J];
    float sum = 0.f;
#pragma unroll
    for (int i = 0; i < J; ++i) {
        const float si = fmaf(p[i], sc, pb[i * H_ + h]);
        e[i] = ok[i] ? __expf(si) : 0.f;   // max-free: |si| ~ O(6), f32-safe
        sum += e[i];
    }

    // ---- phase rotation of channels 0..3 (grp==0 lanes only) ----------------
    if (grp == 0) {
#pragma unroll
        for (int pi = 0; pi < 8; ++pi) {
            const int i = pi + 4;
            const float b0 = phase_base[(pi * H_ + h) * 2 + 0];
            const float b1 = phase_base[(pi * H_ + h) * 2 + 1];
            const float g0 = phase_gain[(pi * H_ + h) * 2 + 0];
            const float g1 = phase_gain[(pi * H_ + h) * 2 + 1];
            const float th0 = fmaf(g0, yp.x * zr[pi].x, b0);
            const float th1 = fmaf(g1, yp.y * zr[pi].y, b1);
            const float c0 = __cosf(th0), s0 = __sinf(th0);
            const float c1 = __cosf(th1), s1 = __sinf(th1);
            const float v0 = vr[i].x, v1 = vr[i].y, v2 = vr[i].z, v3 = vr[i].w;
            vr[i].x = c0 * v0 - s0 * v1;
            vr[i].y = s0 * v0 + c0 * v1;
            vr[i].z = c1 * v2 - s1 * v3;
            vr[i].w = s1 * v2 + c1 * v3;
        }
    }

    // ---- weighted sum --------------------------------------------------------
    float4 acc = make_float4(0.f, 0.f, 0.f, 0.f);
#pragma unroll
    for (int i = 0; i < J; ++i) {
        acc.x = fmaf(e[i], vr[i].x, acc.x);
        acc.y = fmaf(e[i], vr[i].y, acc.y);
        acc.z = fmaf(e[i], vr[i].z, acc.z);
        acc.w = fmaf(e[i], vr[i].w, acc.w);
    }

    float4 res;
    if (n >= 1) {                    // offset d=1 valid -> sum >= e[0] > 0
        const float inv = __builtin_amdgcn_rcpf(sum);   // ~1 ulp, tol is 2^-7
        res = make_float4(acc.x * inv, acc.y * inv, acc.z * inv, acc.w * inv);
    } else {                         // n==0: no valid offset -> zeros
        res = make_float4(0.f, 0.f, 0.f, 0.f);
    }
    *(float4*)(ob + rowb) = res;
}

} // namespace

extern "C" void kernel_launch(void* const* d_in, const int* in_sizes, int n_in,
                              void* d_out, int out_size, void* d_ws, size_t ws_size,
                              hipStream_t stream) {
    const float* q          = (const float*)d_in[0];
    const float* k          = (const float*)d_in[1];
    const float* v          = (const float*)d_in[2];
    const float* pb         = (const float*)d_in[3];
    const float* se         = (const float*)d_in[4];
    const float* phase_base = (const float*)d_in[5];
    const float* phase_gain = (const float*)d_in[6];
    const float* y_pre      = (const float*)d_in[7];
    const float* z_pre      = (const float*)d_in[8];
    float* out              = (float*)d_out;

    const int positions = B_ * H_ * N_;          // 131072
    const int blocks    = positions / 16;        // 16 positions per 256-thread block
    dsqg_kernel<<<blocks, 256, 0, stream>>>(q, k, v, pb, se, phase_base,
                                            phase_gain, y_pre, z_pre, out);
}

// Round 2
// 185.318 us; speedup vs baseline: 1.0505x; 1.0290x over previous
//
#include <hip/hip_runtime.h>

// DSQG attention, J=12 causal offsets, f32.
// One 16-lane group per position; lane holds 4 channels (float4).
// R4: single-latency-exposure fix. R3 post-mortem showed the compiler
// serialized the 24 k/v row loads (VGPR=80, per-wave stall ~12k cyc ~= 24
// loads x ~500 cyc). Changes:
//   * __builtin_amdgcn_sched_barrier(0) pins ALL global loads (q, 12 k,
//     12 v, y/z) before ANY consumption -> one vmcnt wait per wave.
//   * se table (12x64 f32, globally uniform, 3 KB) staged to LDS once per
//     block; read as ds_read_b128 in the dot loop (lgkm-counted, hidden
//     under the vmcnt wait). Keeps peak VGPR pressure ~135 < 168 cap.
//   * everything else identical to R3 (DPP 16-lane allreduce, max-free
//     softmax, grp==0 phase rotation, v_rcp normalize).

namespace {

constexpr int J   = 12;
constexpr int B_  = 2;
constexpr int H_  = 16;
constexpr int N_  = 4096;
constexpr int HD_ = 64;
constexpr int OFFS[J] = {1, 2, 4, 8, 16, 64, 96, 192, 384, 512, 768, 1024};

// p += dpp_mov(p); CTRL must be an ICE, hence the template.
template <int CTRL>
__device__ __forceinline__ float dpp_add(float x) {
    int s = __builtin_amdgcn_update_dpp(0, __builtin_bit_cast(int, x),
                                        CTRL, 0xF, 0xF, false);
    return x + __builtin_bit_cast(float, s);
}

__global__ __launch_bounds__(256, 3) void dsqg_kernel(
    const float* __restrict__ q, const float* __restrict__ k,
    const float* __restrict__ v, const float* __restrict__ pb,
    const float* __restrict__ se, const float* __restrict__ phase_base,
    const float* __restrict__ phase_gain, const float* __restrict__ y_pre,
    const float* __restrict__ z_pre, float* __restrict__ out)
{
    __shared__ float4 seS[J * 16];     // 3 KB: se fragments, [i][grp]

    // XCD-locality swizzle: contiguous work range per XCD so k/v row re-reads
    // (reuse window <= 1024 rows = 512 KB) stay in that XCD's 4 MB L2.
    const int raw = blockIdx.x;
    const int per = gridDim.x >> 3;
    const int wid = (raw & 7) * per + (raw >> 3);

    const int bh    = wid >> 8;       // 256 blocks (16 positions each) per (b,h)
    const int chunk = wid & 255;
    const int h     = bh & (H_ - 1);

    const int tid  = threadIdx.x;
    const int lane = tid & 63;
    const int wave = tid >> 6;
    const int grp  = lane & 15;                        // lane within position group
    const int n    = chunk * 16 + wave * 4 + (lane >> 4);

    // stage se into LDS (uniform table, L2-hot after first block)
    if (tid < J * 16) seS[tid] = ((const float4*)se)[tid];

    // uniform (SGPR) per-(b,h) base pointers; per-lane 32-bit byte offsets
    const size_t bhbytes = (size_t)bh * (N_ * HD_ * 4);
    const char* qb = (const char*)q + bhbytes;
    const char* kb = (const char*)k + bhbytes;
    const char* vb = (const char*)v + bhbytes;
    char*       ob = (char*)out + bhbytes;

    const uint32_t gb   = (uint32_t)grp << 4;              // lane's float4 in a row
    const uint32_t rowb = ((uint32_t)n << 8) + gb;         // this position's slot

    bool ok[J];
    uint32_t offb[J];                 // byte offset of k/v row slot (clamped)
#pragma unroll
    for (int i = 0; i < J; ++i) {
        ok[i]   = (n >= OFFS[i]);
        offb[i] = ok[i] ? (rowb - ((uint32_t)OFFS[i] << 8)) : gb;
    }

    __syncthreads();                  // seS ready (placed BEFORE load cluster)

    // ---- issue ALL global loads; nothing below may be hoisted above ---------
    const float4 qr = *(const float4*)(qb + rowb);

    float4 kr[J];
#pragma unroll
    for (int i = 0; i < J; ++i) kr[i] = *(const float4*)(kb + offb[i]);

    float4 vr[J];
#pragma unroll
    for (int i = 0; i < J; ++i) vr[i] = *(const float4*)(vb + offb[i]);

    float2 zr[8];
    float2 yp = make_float2(0.f, 0.f);
    if (grp == 0) {                   // phase features only needed on ch0-3 lanes
        const char* yb = (const char*)y_pre + (size_t)bh * (N_ * 8);
        const char* zb = (const char*)z_pre + (size_t)bh * (N_ * 8);
        const uint32_t nb8 = (uint32_t)n << 3;
        yp = *(const float2*)(yb + nb8);
#pragma unroll
        for (int pi = 0; pi < 8; ++pi) {
            const uint32_t zo =
                ok[pi + 4] ? (nb8 - ((uint32_t)OFFS[pi + 4] << 3)) : 0u;
            zr[pi] = *(const float2*)(zb + zo);
        }
    }

    __builtin_amdgcn_sched_barrier(0);   // loads above, consumption below

    // ---- partial dots: p_i = q . (k_i + se_i) (per-lane 4-channel partial) --
    float p[J];
#pragma unroll
    for (int i = 0; i < J; ++i) {
        const float4 seg = seS[i * 16 + grp];     // ds_read_b128, lgkm-hidden
        float t = qr.x * (kr[i].x + seg.x);
        t = fmaf(qr.y, kr[i].y + seg.y, t);
        t = fmaf(qr.z, kr[i].z + seg.z, t);
        p[i] = fmaf(qr.w, kr[i].w + seg.w, t);
    }

    // ---- 16-lane allreduce, pure VALU DPP (no cross-lane LDS traffic) -------
    // xor1, xor2 (quad_perm) reduce within quads; ror4+ror8 sum the 4
    // replicated quad-sums across the row -> every lane holds the full dot.
#pragma unroll
    for (int i = 0; i < J; ++i) {
        p[i] = dpp_add<0xB1>(p[i]);    // quad_perm [1,0,3,2]  : xor 1
        p[i] = dpp_add<0x4E>(p[i]);    // quad_perm [2,3,0,1]  : xor 2
        p[i] = dpp_add<0x124>(p[i]);   // row_ror:4
        p[i] = dpp_add<0x128>(p[i]);   // row_ror:8
    }

    const float sc = 0.125f;  // 1/sqrt(64)
    float e[J];
    float sum = 0.f;
#pragma unroll
    for (int i = 0; i < J; ++i) {
        const float si = fmaf(p[i], sc, pb[i * H_ + h]);
        e[i] = ok[i] ? __expf(si) : 0.f;   // max-free: |si| ~ O(6), f32-safe
        sum += e[i];
    }

    // ---- phase rotation of channels 0..3 (grp==0 lanes only) ----------------
    if (grp == 0) {
#pragma unroll
        for (int pi = 0; pi < 8; ++pi) {
            const int i = pi + 4;
            const float b0 = phase_base[(pi * H_ + h) * 2 + 0];
            const float b1 = phase_base[(pi * H_ + h) * 2 + 1];
            const float g0 = phase_gain[(pi * H_ + h) * 2 + 0];
            const float g1 = phase_gain[(pi * H_ + h) * 2 + 1];
            const float th0 = fmaf(g0, yp.x * zr[pi].x, b0);
            const float th1 = fmaf(g1, yp.y * zr[pi].y, b1);
            const float c0 = __cosf(th0), s0 = __sinf(th0);
            const float c1 = __cosf(th1), s1 = __sinf(th1);
            const float v0 = vr[i].x, v1 = vr[i].y, v2 = vr[i].z, v3 = vr[i].w;
            vr[i].x = c0 * v0 - s0 * v1;
            vr[i].y = s0 * v0 + c0 * v1;
            vr[i].z = c1 * v2 - s1 * v3;
            vr[i].w = s1 * v2 + c1 * v3;
        }
    }

    // ---- weighted sum --------------------------------------------------------
    float4 acc = make_float4(0.f, 0.f, 0.f, 0.f);
#pragma unroll
    for (int i = 0; i < J; ++i) {
        acc.x = fmaf(e[i], vr[i].x, acc.x);
        acc.y = fmaf(e[i], vr[i].y, acc.y);
        acc.z = fmaf(e[i], vr[i].z, acc.z);
        acc.w = fmaf(e[i], vr[i].w, acc.w);
    }

    float4 res;
    if (n >= 1) {                    // offset d=1 valid -> sum >= e[0] > 0
        const float inv = __builtin_amdgcn_rcpf(sum);   // ~1 ulp, tol is 2^-7
        res = make_float4(acc.x * inv, acc.y * inv, acc.z * inv, acc.w * inv);
    } else {                         // n==0: no valid offset -> zeros
        res = make_float4(0.f, 0.f, 0.f, 0.f);
    }
    *(float4*)(ob + rowb) = res;
}

} // namespace

extern "C" void kernel_launch(void* const* d_in, const int* in_sizes, int n_in,
                              void* d_out, int out_size, void* d_ws, size_t ws_size,
                              hipStream_t stream) {
    const float* q          = (const float*)d_in[0];
    const float* k          = (const float*)d_in[1];
    const float* v          = (const float*)d_in[2];
    const float* pb         = (const float*)d_in[3];
    const float* se         = (const float*)d_in[4];
    const float* phase_base = (const float*)d_in[5];
    const float* phase_gain = (const float*)d_in[6];
    const float* y_pre      = (const float*)d_in[7];
    const float* z_pre      = (const float*)d_in[8];
    float* out              = (float*)d_out;

    const int positions = B_ * H_ * N_;          // 131072
    const int blocks    = positions / 16;        // 16 positions per 256-thread block
    dsqg_kernel<<<blocks, 256, 0, stream>>>(q, k, v, pb, se, phase_base,
                                            phase_gain, y_pre, z_pre, out);
}

// Round 3
// 178.790 us; speedup vs baseline: 1.0888x; 1.0365x over previous
//
#include <hip/hip_runtime.h>

// DSQG attention, J=12 causal offsets, f32.
// One 16-lane group per position; lane holds 4 channels (float4).
// R5: inline-asm load batch. R3/R4 post-mortems proved hipcc serializes the
// 24 k/v row loads no matter what the source says (VGPR=72 < the 96 needed
// for the results alone). Fix per the documented HipKittens pattern:
//   * ALL 34 global loads (q, 12 k, 12 v, y, 8 z) issued as asm volatile
//     global_load_dwordx4/x2 with "=v" pinned destinations -> RA must keep
//     them live -> ONE latency exposure per wave instead of ~24.
//   * manual counted waits: s_waitcnt vmcnt(21) (q+k done) -> dot/DPP/softmax
//     compute covers the v/y/z tail -> s_waitcnt vmcnt(0) -> rotation+sum.
//     sched_barrier(0) after each wait (rule: compiler hoists reg-only VALU
//     past inline-asm waitcnt otherwise).
//   * y/z loads made unconditional (deterministic vmcnt count; addresses are
//     clamped-safe; 16 lanes/position read the same 8 B -> broadcast).
//   * se table in LDS (R4), DPP 16-lane allreduce (R3), max-free softmax,
//     v_rcp normalize unchanged.
// Hazard watched in post-mortem: RA spill between load and wait would be
// silent corruption -> absmax / WRITE_SIZE are the tripwires.

namespace {

constexpr int J   = 12;
constexpr int B_  = 2;
constexpr int H_  = 16;
constexpr int N_  = 4096;
constexpr int HD_ = 64;
constexpr int OFFS[J] = {1, 2, 4, 8, 16, 64, 96, 192, 384, 512, 768, 1024};

using f32x4 = __attribute__((ext_vector_type(4))) float;
using f32x2 = __attribute__((ext_vector_type(2))) float;

#define GLOAD4(dst, off, base)                                              \
    asm volatile("global_load_dwordx4 %0, %1, %2"                           \
                 : "=v"(dst) : "v"(off), "s"(base) : "memory")
#define GLOAD2(dst, off, base)                                              \
    asm volatile("global_load_dwordx2 %0, %1, %2"                           \
                 : "=v"(dst) : "v"(off), "s"(base) : "memory")

// p += dpp_mov(p); CTRL must be an ICE, hence the template.
template <int CTRL>
__device__ __forceinline__ float dpp_add(float x) {
    int s = __builtin_amdgcn_update_dpp(0, __builtin_bit_cast(int, x),
                                        CTRL, 0xF, 0xF, false);
    return x + __builtin_bit_cast(float, s);
}

__global__ __launch_bounds__(256, 3) void dsqg_kernel(
    const float* __restrict__ q, const float* __restrict__ k,
    const float* __restrict__ v, const float* __restrict__ pb,
    const float* __restrict__ se, const float* __restrict__ phase_base,
    const float* __restrict__ phase_gain, const float* __restrict__ y_pre,
    const float* __restrict__ z_pre, float* __restrict__ out)
{
    __shared__ f32x4 seS[J * 16];     // 3 KB: se fragments, [i][grp]

    // XCD-locality swizzle: contiguous work range per XCD so k/v row re-reads
    // (reuse window <= 1024 rows = 512 KB) stay in that XCD's 4 MB L2.
    const int raw = blockIdx.x;
    const int per = gridDim.x >> 3;
    const int wid = (raw & 7) * per + (raw >> 3);

    const int bh    = wid >> 8;       // 256 blocks (16 positions each) per (b,h)
    const int chunk = wid & 255;
    const int h     = bh & (H_ - 1);

    const int tid  = threadIdx.x;
    const int lane = tid & 63;
    const int wave = tid >> 6;
    const int grp  = lane & 15;                        // lane within position group
    const int n    = chunk * 16 + wave * 4 + (lane >> 4);

    // stage se into LDS (uniform table, L2-hot after first block)
    if (tid < J * 16) seS[tid] = ((const f32x4*)se)[tid];

    // uniform (SGPR) per-(b,h) base pointers; per-lane 32-bit byte offsets
    const size_t bhbytes = (size_t)bh * (N_ * HD_ * 4);
    const char* qb = (const char*)q + bhbytes;
    const char* kb = (const char*)k + bhbytes;
    const char* vb = (const char*)v + bhbytes;
    char*       ob = (char*)out + bhbytes;
    const char* yb = (const char*)y_pre + (size_t)bh * (N_ * 8);
    const char* zb = (const char*)z_pre + (size_t)bh * (N_ * 8);

    const uint32_t gb   = (uint32_t)grp << 4;              // lane's float4 in a row
    const uint32_t rowb = ((uint32_t)n << 8) + gb;         // this position's slot
    const uint32_t nb8  = (uint32_t)n << 3;

    bool ok[J];
    uint32_t offb[J];                 // byte offset of k/v row slot (clamped)
#pragma unroll
    for (int i = 0; i < J; ++i) {
        ok[i]   = (n >= OFFS[i]);
        offb[i] = ok[i] ? (rowb - ((uint32_t)OFFS[i] << 8)) : gb;
    }
    uint32_t zo[8];
#pragma unroll
    for (int pi = 0; pi < 8; ++pi)
        zo[pi] = ok[pi + 4] ? (nb8 - ((uint32_t)OFFS[pi + 4] << 3)) : 0u;

    __syncthreads();                  // seS ready; MUST precede the load batch
                                      // (compiler drains counters at barriers)

    // ---- issue ALL 34 global loads back-to-back (asm-pinned dests) ----------
    f32x4 qr;
    GLOAD4(qr, rowb, qb);                                  // 1 outstanding

    f32x4 kr[J];
#pragma unroll
    for (int i = 0; i < J; ++i) GLOAD4(kr[i], offb[i], kb);   // 13

    f32x4 vr[J];
#pragma unroll
    for (int i = 0; i < J; ++i) GLOAD4(vr[i], offb[i], vb);   // 25

    f32x2 yp;
    GLOAD2(yp, nb8, yb);                                   // 26
    f32x2 zr[8];
#pragma unroll
    for (int pi = 0; pi < 8; ++pi) GLOAD2(zr[pi], zo[pi], zb);   // 34

    // ---- wait for q + k (34-13 = 21 may remain outstanding) -----------------
    asm volatile("s_waitcnt vmcnt(21)" ::: "memory");
    __builtin_amdgcn_sched_barrier(0);

    // partial dots: p_i = q . (k_i + se_i)  (per-lane 4-channel partial)
    float p[J];
#pragma unroll
    for (int i = 0; i < J; ++i) {
        const f32x4 seg = seS[i * 16 + grp];     // ds_read_b128, lgkm-managed
        float t = qr.x * (kr[i].x + seg.x);
        t = fmaf(qr.y, kr[i].y + seg.y, t);
        t = fmaf(qr.z, kr[i].z + seg.z, t);
        p[i] = fmaf(qr.w, kr[i].w + seg.w, t);
    }

    // 16-lane allreduce, pure VALU DPP: xor1, xor2 within quads; ror4+ror8
    // across the row -> every lane holds the full dot.
#pragma unroll
    for (int i = 0; i < J; ++i) {
        p[i] = dpp_add<0xB1>(p[i]);    // quad_perm [1,0,3,2]  : xor 1
        p[i] = dpp_add<0x4E>(p[i]);    // quad_perm [2,3,0,1]  : xor 2
        p[i] = dpp_add<0x124>(p[i]);   // row_ror:4
        p[i] = dpp_add<0x128>(p[i]);   // row_ror:8
    }

    const float sc = 0.125f;  // 1/sqrt(64)
    float e[J];
    float sum = 0.f;
#pragma unroll
    for (int i = 0; i < J; ++i) {
        const float si = fmaf(p[i], sc, pb[i * H_ + h]);
        e[i] = ok[i] ? __expf(si) : 0.f;   // max-free: |si| ~ O(6), f32-safe
        sum += e[i];
    }

    // ---- wait for v + y + z; compute above covered most of their latency ----
    asm volatile("s_waitcnt vmcnt(0)" ::: "memory");
    __builtin_amdgcn_sched_barrier(0);

    // phase rotation of channels 0..3 (grp==0 lanes only)
    if (grp == 0) {
#pragma unroll
        for (int pi = 0; pi < 8; ++pi) {
            const int i = pi + 4;
            const float b0 = phase_base[(pi * H_ + h) * 2 + 0];
            const float b1 = phase_base[(pi * H_ + h) * 2 + 1];
            const float g0 = phase_gain[(pi * H_ + h) * 2 + 0];
            const float g1 = phase_gain[(pi * H_ + h) * 2 + 1];
            const float th0 = fmaf(g0, yp.x * zr[pi].x, b0);
            const float th1 = fmaf(g1, yp.y * zr[pi].y, b1);
            const float c0 = __cosf(th0), s0 = __sinf(th0);
            const float c1 = __cosf(th1), s1 = __sinf(th1);
            const float v0 = vr[i].x, v1 = vr[i].y, v2 = vr[i].z, v3 = vr[i].w;
            vr[i].x = c0 * v0 - s0 * v1;
            vr[i].y = s0 * v0 + c0 * v1;
            vr[i].z = c1 * v2 - s1 * v3;
            vr[i].w = s1 * v2 + c1 * v3;
        }
    }

    // weighted sum
    float4 acc = make_float4(0.f, 0.f, 0.f, 0.f);
#pragma unroll
    for (int i = 0; i < J; ++i) {
        acc.x = fmaf(e[i], vr[i].x, acc.x);
        acc.y = fmaf(e[i], vr[i].y, acc.y);
        acc.z = fmaf(e[i], vr[i].z, acc.z);
        acc.w = fmaf(e[i], vr[i].w, acc.w);
    }

    float4 res;
    if (n >= 1) {                    // offset d=1 valid -> sum >= e[0] > 0
        const float inv = __builtin_amdgcn_rcpf(sum);   // ~1 ulp, tol is 2^-7
        res = make_float4(acc.x * inv, acc.y * inv, acc.z * inv, acc.w * inv);
    } else {                         // n==0: no valid offset -> zeros
        res = make_float4(0.f, 0.f, 0.f, 0.f);
    }
    *(float4*)(ob + rowb) = res;
}

} // namespace

extern "C" void kernel_launch(void* const* d_in, const int* in_sizes, int n_in,
                              void* d_out, int out_size, void* d_ws, size_t ws_size,
                              hipStream_t stream) {
    const float* q          = (const float*)d_in[0];
    const float* k          = (const float*)d_in[1];
    const float* v          = (const float*)d_in[2];
    const float* pb         = (const float*)d_in[3];
    const float* se         = (const float*)d_in[4];
    const float* phase_base = (const float*)d_in[5];
    const float* phase_gain = (const float*)d_in[6];
    const float* y_pre      = (const float*)d_in[7];
    const float* z_pre      = (const float*)d_in[8];
    float* out              = (float*)d_out;

    const int positions = B_ * H_ * N_;          // 131072
    const int blocks    = positions / 16;        // 16 positions per 256-thread block
    dsqg_kernel<<<blocks, 256, 0, stream>>>(q, k, v, pb, se, phase_base,
                                            phase_gain, y_pre, z_pre, out);
}